// Round 1
// baseline (1158.592 us; speedup 1.0000x reference)
//
#include <hip/hip_runtime.h>

#define GCN_N 100000
#define GCN_H 128

// ---------------- CSR build ----------------

__global__ __launch_bounds__(256) void count_kernel(const int* __restrict__ dst,
                                                    int* __restrict__ counts, int E) {
    int e = blockIdx.x * 256 + threadIdx.x;
    if (e < E) atomicAdd(&counts[dst[e]], 1);
}

__global__ __launch_bounds__(1024) void scan_kernel(const int* __restrict__ counts,
                                                    int* __restrict__ rowptr,
                                                    float* __restrict__ dis, int n) {
    __shared__ int wsums[16];
    __shared__ int s_running;
    int tid = threadIdx.x;
    int lane = tid & 63, wid = tid >> 6;
    if (tid == 0) s_running = 0;
    __syncthreads();
    for (int base = 0; base < n; base += 1024) {
        int idx = base + tid;
        int v = (idx < n) ? counts[idx] : 0;
        int iv = v;
        #pragma unroll
        for (int d = 1; d < 64; d <<= 1) {
            int x = __shfl_up(iv, d, 64);
            if (lane >= d) iv += x;
        }
        if (lane == 63) wsums[wid] = iv;
        __syncthreads();
        if (wid == 0) {
            int wv = (lane < 16) ? wsums[lane] : 0;
            #pragma unroll
            for (int d = 1; d < 16; d <<= 1) {
                int x = __shfl_up(wv, d, 64);
                if (lane >= d) wv += x;
            }
            if (lane < 16) wsums[lane] = wv;
        }
        __syncthreads();
        int woff = (wid > 0) ? wsums[wid - 1] : 0;
        int run = s_running;
        if (idx < n) {
            rowptr[idx] = run + woff + iv - v;          // exclusive scan
            dis[idx] = rsqrtf((float)(v + 1));          // deg = indeg + self-loop
        }
        __syncthreads();
        if (tid == 0) s_running = run + wsums[15];
        __syncthreads();
    }
    if (tid == 0) rowptr[n] = s_running;
}

__global__ __launch_bounds__(256) void fill_kernel(const int* __restrict__ src,
                                                   const int* __restrict__ dst,
                                                   const int* __restrict__ rowptr,
                                                   int* __restrict__ cursor,
                                                   int* __restrict__ csrc, int E) {
    int e = blockIdx.x * 256 + threadIdx.x;
    if (e < E) {
        int d = dst[e];
        int pos = rowptr[d] + atomicAdd(&cursor[d], 1);
        csrc[pos] = src[e];
    }
}

// ---------------- dense matmuls ----------------

// t = x @ W0, x: [N,5], W0: [5,128]. 8 rows/block, 32 threads/row (float4 cols).
__global__ __launch_bounds__(256) void mm0_kernel(const float* __restrict__ x,
                                                  const float* __restrict__ W0,
                                                  float* __restrict__ out, int n) {
    __shared__ __align__(16) float sW[5 * 128];
    int tid = threadIdx.x;
    for (int i = tid; i < 5 * 128; i += 256) sW[i] = W0[i];
    __syncthreads();
    int group = tid >> 5, lane = tid & 31;
    int row = blockIdx.x * 8 + group;
    if (row >= n) return;
    float xv[5];
    #pragma unroll
    for (int k = 0; k < 5; k++) xv[k] = x[(size_t)row * 5 + k];
    float4 acc = make_float4(0.f, 0.f, 0.f, 0.f);
    #pragma unroll
    for (int k = 0; k < 5; k++) {
        float4 w = ((const float4*)(sW + k * 128))[lane];
        acc.x = fmaf(xv[k], w.x, acc.x);
        acc.y = fmaf(xv[k], w.y, acc.y);
        acc.z = fmaf(xv[k], w.z, acc.z);
        acc.w = fmaf(xv[k], w.w, acc.w);
    }
    ((float4*)(out + (size_t)row * GCN_H))[lane] = acc;
}

// out = act(in) @ W, in/out: [N,128], W: [128,128]. 32 rows/block,
// 8 groups of 32 lanes, each group owns 4 rows (register blocking on rows).
__global__ __launch_bounds__(256) void mm128_kernel(const float* __restrict__ in,
                                                    const float* __restrict__ W,
                                                    float* __restrict__ out, int n,
                                                    int relu) {
    __shared__ __align__(16) float sW[128 * 128];   // 64 KB
    __shared__ __align__(16) float sIn[32 * 128];   // 16 KB
    int tid = threadIdx.x;
    const float4* W4 = (const float4*)W;
    float4* sW4 = (float4*)sW;
    for (int i = tid; i < 128 * 32; i += 256) sW4[i] = W4[i];
    // stage 32 input rows (with optional relu)
    int rowBase = blockIdx.x * 32;
    #pragma unroll
    for (int j = 0; j < 4; j++) {
        int f = tid + j * 256;          // flat float4 index, 0..1023
        int r = f >> 5, c4 = f & 31;
        float4 v = ((const float4*)(in + (size_t)(rowBase + r) * GCN_H))[c4];
        if (relu) {
            v.x = fmaxf(v.x, 0.f); v.y = fmaxf(v.y, 0.f);
            v.z = fmaxf(v.z, 0.f); v.w = fmaxf(v.w, 0.f);
        }
        ((float4*)(sIn + r * 128))[c4] = v;
    }
    __syncthreads();

    int group = tid >> 5, lane = tid & 31;
    int r0 = group * 4;
    float4 acc0 = make_float4(0.f,0.f,0.f,0.f);
    float4 acc1 = make_float4(0.f,0.f,0.f,0.f);
    float4 acc2 = make_float4(0.f,0.f,0.f,0.f);
    float4 acc3 = make_float4(0.f,0.f,0.f,0.f);
    const float* a0p = sIn + (r0 + 0) * 128;
    const float* a1p = sIn + (r0 + 1) * 128;
    const float* a2p = sIn + (r0 + 2) * 128;
    const float* a3p = sIn + (r0 + 3) * 128;
    #pragma unroll 8
    for (int k = 0; k < 128; k++) {
        float4 w = sW4[k * 32 + lane];
        float a0 = a0p[k], a1 = a1p[k], a2 = a2p[k], a3 = a3p[k];
        acc0.x = fmaf(a0, w.x, acc0.x); acc0.y = fmaf(a0, w.y, acc0.y);
        acc0.z = fmaf(a0, w.z, acc0.z); acc0.w = fmaf(a0, w.w, acc0.w);
        acc1.x = fmaf(a1, w.x, acc1.x); acc1.y = fmaf(a1, w.y, acc1.y);
        acc1.z = fmaf(a1, w.z, acc1.z); acc1.w = fmaf(a1, w.w, acc1.w);
        acc2.x = fmaf(a2, w.x, acc2.x); acc2.y = fmaf(a2, w.y, acc2.y);
        acc2.z = fmaf(a2, w.z, acc2.z); acc2.w = fmaf(a2, w.w, acc2.w);
        acc3.x = fmaf(a3, w.x, acc3.x); acc3.y = fmaf(a3, w.y, acc3.y);
        acc3.z = fmaf(a3, w.z, acc3.z); acc3.w = fmaf(a3, w.w, acc3.w);
    }
    ((float4*)(out + (size_t)(rowBase + r0 + 0) * GCN_H))[lane] = acc0;
    ((float4*)(out + (size_t)(rowBase + r0 + 1) * GCN_H))[lane] = acc1;
    ((float4*)(out + (size_t)(rowBase + r0 + 2) * GCN_H))[lane] = acc2;
    ((float4*)(out + (size_t)(rowBase + r0 + 3) * GCN_H))[lane] = acc3;
}

// ---------------- sparse aggregation ----------------
// out[i] = bias + dis[i]^2 * t[i] + sum_{e: dst=i} dis[src]*dis[i] * t[src]
// 8 nodes/block, 32 lanes/node, float4 per lane.
__global__ __launch_bounds__(256) void agg_kernel(const float* __restrict__ t,
                                                  const float* __restrict__ dis,
                                                  const int* __restrict__ rowptr,
                                                  const int* __restrict__ csrc,
                                                  const float* __restrict__ bias,
                                                  float* __restrict__ out, int n) {
    int group = threadIdx.x >> 5, lane = threadIdx.x & 31;
    int i = blockIdx.x * 8 + group;
    if (i >= n) return;
    const float4* t4 = (const float4*)t;
    float di = dis[i];
    float4 tv = t4[(size_t)i * 32 + lane];
    float4 b4 = ((const float4*)bias)[lane];
    float self = di * di;
    float4 acc;
    acc.x = fmaf(self, tv.x, b4.x);
    acc.y = fmaf(self, tv.y, b4.y);
    acc.z = fmaf(self, tv.z, b4.z);
    acc.w = fmaf(self, tv.w, b4.w);
    int r0 = rowptr[i], r1 = rowptr[i + 1];
    for (int e = r0; e < r1; e++) {
        int s = csrc[e];
        float ns = dis[s] * di;
        float4 sv = t4[(size_t)s * 32 + lane];
        acc.x = fmaf(ns, sv.x, acc.x);
        acc.y = fmaf(ns, sv.y, acc.y);
        acc.z = fmaf(ns, sv.z, acc.z);
        acc.w = fmaf(ns, sv.w, acc.w);
    }
    ((float4*)(out + (size_t)i * GCN_H))[lane] = acc;
}

// ---------------- pooling + head ----------------
// per node: dot(h[i], lin_w) -> atomicAdd into per-graph sum; count nodes.
__global__ __launch_bounds__(256) void pool_kernel(const float* __restrict__ h,
                                                   const int* __restrict__ batch,
                                                   const float* __restrict__ lw,
                                                   float* __restrict__ gsum,
                                                   int* __restrict__ gcnt, int n) {
    int wid = threadIdx.x >> 6, lane = threadIdx.x & 63;
    int i = blockIdx.x * 4 + wid;
    if (i >= n) return;
    float2 hv = ((const float2*)(h + (size_t)i * GCN_H))[lane];
    float2 wv = ((const float2*)lw)[lane];
    float d = hv.x * wv.x + hv.y * wv.y;
    #pragma unroll
    for (int o = 32; o > 0; o >>= 1) d += __shfl_down(d, o, 64);
    if (lane == 0) {
        int b = batch[i];
        atomicAdd(&gsum[b], d);
        atomicAdd(&gcnt[b], 1);
    }
}

__global__ __launch_bounds__(256) void final_kernel(const float* __restrict__ gsum,
                                                    const int* __restrict__ gcnt,
                                                    const float* __restrict__ lb,
                                                    float* __restrict__ out) {
    int g = threadIdx.x;
    float c = (float)max(gcnt[g], 1);
    float v = gsum[g] / c + lb[0];
    out[g] = 1.f / (1.f + expf(-v));
}

// ---------------- launch ----------------

extern "C" void kernel_launch(void* const* d_in, const int* in_sizes, int n_in,
                              void* d_out, int out_size, void* d_ws, size_t ws_size,
                              hipStream_t stream) {
    const float* x   = (const float*)d_in[0];
    const int*   ei  = (const int*)d_in[1];
    const int*   bat = (const int*)d_in[2];
    const float* W0  = (const float*)d_in[3];
    const float* b0  = (const float*)d_in[4];
    const float* W1  = (const float*)d_in[5];
    const float* b1  = (const float*)d_in[6];
    const float* W2  = (const float*)d_in[7];
    const float* b2  = (const float*)d_in[8];
    const float* lw  = (const float*)d_in[9];
    const float* lb  = (const float*)d_in[10];
    float* out = (float*)d_out;

    const int N = GCN_N;
    const int E = in_sizes[1] / 2;

    char* ws = (char*)d_ws;
    size_t off = 0;
    auto alloc = [&](size_t bytes) {
        size_t o = off;
        off += (bytes + 255) & ~(size_t)255;
        return o;
    };
    int*   counts = (int*)(ws + alloc((size_t)N * 4));
    int*   cursor = (int*)(ws + alloc((size_t)N * 4));
    int*   rowptr = (int*)(ws + alloc((size_t)(N + 1) * 4));
    float* dis    = (float*)(ws + alloc((size_t)N * 4));
    int*   csrc   = (int*)(ws + alloc((size_t)E * 4));
    float* bufA   = (float*)(ws + alloc((size_t)N * GCN_H * 4));
    float* bufB   = (float*)(ws + alloc((size_t)N * GCN_H * 4));
    float* gsum   = (float*)(ws + alloc(256 * 4));
    int*   gcnt   = (int*)(ws + alloc(256 * 4));

    const int* src = ei;
    const int* dst = ei + E;

    hipMemsetAsync(counts, 0, (size_t)N * 4, stream);
    hipMemsetAsync(cursor, 0, (size_t)N * 4, stream);
    hipMemsetAsync(gsum, 0, 256 * 4, stream);
    hipMemsetAsync(gcnt, 0, 256 * 4, stream);

    count_kernel<<<(E + 255) / 256, 256, 0, stream>>>(dst, counts, E);
    scan_kernel<<<1, 1024, 0, stream>>>(counts, rowptr, dis, N);
    fill_kernel<<<(E + 255) / 256, 256, 0, stream>>>(src, dst, rowptr, cursor, csrc, E);

    mm0_kernel<<<N / 8, 256, 0, stream>>>(x, W0, bufA, N);
    agg_kernel<<<N / 8, 256, 0, stream>>>(bufA, dis, rowptr, csrc, b0, bufB, N);
    mm128_kernel<<<N / 32, 256, 0, stream>>>(bufB, W1, bufA, N, 1);
    agg_kernel<<<N / 8, 256, 0, stream>>>(bufA, dis, rowptr, csrc, b1, bufB, N);
    mm128_kernel<<<N / 32, 256, 0, stream>>>(bufB, W2, bufA, N, 1);
    agg_kernel<<<N / 8, 256, 0, stream>>>(bufA, dis, rowptr, csrc, b2, bufB, N);

    pool_kernel<<<N / 4, 256, 0, stream>>>(bufB, bat, lw, gsum, gcnt, N);
    final_kernel<<<1, 256, 0, stream>>>(gsum, gcnt, lb, out);
}

// Round 2
// 746.198 us; speedup vs baseline: 1.5527x; 1.5527x over previous
//
#include <hip/hip_runtime.h>

#define GCN_N 100000
#define GCN_H 128
#define GCN_G 256

// ---------------- CSR build ----------------

__global__ __launch_bounds__(256) void count_kernel(const int* __restrict__ dst,
                                                    int* __restrict__ counts, int E) {
    int e = blockIdx.x * 256 + threadIdx.x;
    if (e < E) atomicAdd(&counts[dst[e]], 1);
}

__global__ __launch_bounds__(1024) void scan_kernel(const int* __restrict__ counts,
                                                    int* __restrict__ rowptr,
                                                    float* __restrict__ dis, int n) {
    __shared__ int wsums[16];
    __shared__ int s_running;
    int tid = threadIdx.x;
    int lane = tid & 63, wid = tid >> 6;
    if (tid == 0) s_running = 0;
    __syncthreads();
    for (int base = 0; base < n; base += 1024) {
        int idx = base + tid;
        int v = (idx < n) ? counts[idx] : 0;
        int iv = v;
        #pragma unroll
        for (int d = 1; d < 64; d <<= 1) {
            int x = __shfl_up(iv, d, 64);
            if (lane >= d) iv += x;
        }
        if (lane == 63) wsums[wid] = iv;
        __syncthreads();
        if (wid == 0) {
            int wv = (lane < 16) ? wsums[lane] : 0;
            #pragma unroll
            for (int d = 1; d < 16; d <<= 1) {
                int x = __shfl_up(wv, d, 64);
                if (lane >= d) wv += x;
            }
            if (lane < 16) wsums[lane] = wv;
        }
        __syncthreads();
        int woff = (wid > 0) ? wsums[wid - 1] : 0;
        int run = s_running;
        if (idx < n) {
            rowptr[idx] = run + woff + iv - v;          // exclusive scan
            dis[idx] = rsqrtf((float)(v + 1));          // deg = indeg + self-loop
        }
        __syncthreads();
        if (tid == 0) s_running = run + wsums[15];
        __syncthreads();
    }
    if (tid == 0) rowptr[n] = s_running;
}

__global__ __launch_bounds__(256) void fill_kernel(const int* __restrict__ src,
                                                   const int* __restrict__ dst,
                                                   const int* __restrict__ rowptr,
                                                   int* __restrict__ cursor,
                                                   int* __restrict__ csrc, int E) {
    int e = blockIdx.x * 256 + threadIdx.x;
    if (e < E) {
        int d = dst[e];
        int pos = rowptr[d] + atomicAdd(&cursor[d], 1);
        csrc[pos] = src[e];
    }
}

// ---------------- dense matmuls (output scaled by dis[row]) ----------------

// t' = dis ⊙ (x @ W0), x: [N,5], W0: [5,128].
__global__ __launch_bounds__(256) void mm0_kernel(const float* __restrict__ x,
                                                  const float* __restrict__ W0,
                                                  const float* __restrict__ dis,
                                                  float* __restrict__ out, int n) {
    __shared__ __align__(16) float sW[5 * 128];
    int tid = threadIdx.x;
    for (int i = tid; i < 5 * 128; i += 256) sW[i] = W0[i];
    __syncthreads();
    int group = tid >> 5, lane = tid & 31;
    int row = blockIdx.x * 8 + group;
    if (row >= n) return;
    float xv[5];
    #pragma unroll
    for (int k = 0; k < 5; k++) xv[k] = x[(size_t)row * 5 + k];
    float4 acc = make_float4(0.f, 0.f, 0.f, 0.f);
    #pragma unroll
    for (int k = 0; k < 5; k++) {
        float4 w = ((const float4*)(sW + k * 128))[lane];
        acc.x = fmaf(xv[k], w.x, acc.x);
        acc.y = fmaf(xv[k], w.y, acc.y);
        acc.z = fmaf(xv[k], w.z, acc.z);
        acc.w = fmaf(xv[k], w.w, acc.w);
    }
    float di = dis[row];
    acc.x *= di; acc.y *= di; acc.z *= di; acc.w *= di;
    ((float4*)(out + (size_t)row * GCN_H))[lane] = acc;
}

// t' = dis ⊙ (act(in) @ W), in: [N,128] (conv output, relu applied on load).
__global__ __launch_bounds__(256) void mm128_kernel(const float* __restrict__ in,
                                                    const float* __restrict__ W,
                                                    const float* __restrict__ dis,
                                                    float* __restrict__ out, int n) {
    __shared__ __align__(16) float sW[128 * 128];   // 64 KB
    __shared__ __align__(16) float sIn[32 * 128];   // 16 KB
    int tid = threadIdx.x;
    const float4* W4 = (const float4*)W;
    float4* sW4 = (float4*)sW;
    for (int i = tid; i < 128 * 32; i += 256) sW4[i] = W4[i];
    int rowBase = blockIdx.x * 32;
    #pragma unroll
    for (int j = 0; j < 4; j++) {
        int f = tid + j * 256;          // flat float4 index, 0..1023
        int r = f >> 5, c4 = f & 31;
        float4 v = ((const float4*)(in + (size_t)(rowBase + r) * GCN_H))[c4];
        v.x = fmaxf(v.x, 0.f); v.y = fmaxf(v.y, 0.f);
        v.z = fmaxf(v.z, 0.f); v.w = fmaxf(v.w, 0.f);
        ((float4*)(sIn + r * 128))[c4] = v;
    }
    __syncthreads();

    int group = tid >> 5, lane = tid & 31;
    int r0 = group * 4;
    float4 acc0 = make_float4(0.f,0.f,0.f,0.f);
    float4 acc1 = make_float4(0.f,0.f,0.f,0.f);
    float4 acc2 = make_float4(0.f,0.f,0.f,0.f);
    float4 acc3 = make_float4(0.f,0.f,0.f,0.f);
    const float* a0p = sIn + (r0 + 0) * 128;
    const float* a1p = sIn + (r0 + 1) * 128;
    const float* a2p = sIn + (r0 + 2) * 128;
    const float* a3p = sIn + (r0 + 3) * 128;
    #pragma unroll 8
    for (int k = 0; k < 128; k++) {
        float4 w = sW4[k * 32 + lane];
        float a0 = a0p[k], a1 = a1p[k], a2 = a2p[k], a3 = a3p[k];
        acc0.x = fmaf(a0, w.x, acc0.x); acc0.y = fmaf(a0, w.y, acc0.y);
        acc0.z = fmaf(a0, w.z, acc0.z); acc0.w = fmaf(a0, w.w, acc0.w);
        acc1.x = fmaf(a1, w.x, acc1.x); acc1.y = fmaf(a1, w.y, acc1.y);
        acc1.z = fmaf(a1, w.z, acc1.z); acc1.w = fmaf(a1, w.w, acc1.w);
        acc2.x = fmaf(a2, w.x, acc2.x); acc2.y = fmaf(a2, w.y, acc2.y);
        acc2.z = fmaf(a2, w.z, acc2.z); acc2.w = fmaf(a2, w.w, acc2.w);
        acc3.x = fmaf(a3, w.x, acc3.x); acc3.y = fmaf(a3, w.y, acc3.y);
        acc3.z = fmaf(a3, w.z, acc3.z); acc3.w = fmaf(a3, w.w, acc3.w);
    }
    float d0 = dis[rowBase + r0 + 0], d1 = dis[rowBase + r0 + 1];
    float d2 = dis[rowBase + r0 + 2], d3 = dis[rowBase + r0 + 3];
    acc0.x *= d0; acc0.y *= d0; acc0.z *= d0; acc0.w *= d0;
    acc1.x *= d1; acc1.y *= d1; acc1.z *= d1; acc1.w *= d1;
    acc2.x *= d2; acc2.y *= d2; acc2.z *= d2; acc2.w *= d2;
    acc3.x *= d3; acc3.y *= d3; acc3.z *= d3; acc3.w *= d3;
    ((float4*)(out + (size_t)(rowBase + r0 + 0) * GCN_H))[lane] = acc0;
    ((float4*)(out + (size_t)(rowBase + r0 + 1) * GCN_H))[lane] = acc1;
    ((float4*)(out + (size_t)(rowBase + r0 + 2) * GCN_H))[lane] = acc2;
    ((float4*)(out + (size_t)(rowBase + r0 + 3) * GCN_H))[lane] = acc3;
}

// ---------------- sparse aggregation ----------------
// conv_out[i] = bias + dis[i] * (t'[i] + sum_{e: dst=i} t'[src])
// FINAL=0: write conv_out rows. FINAL=1: write only dot(conv_out[i], lin_w).
template <int FINAL>
__global__ __launch_bounds__(256) void agg_kernel(const float* __restrict__ t,
                                                  const float* __restrict__ dis,
                                                  const int* __restrict__ rowptr,
                                                  const int* __restrict__ csrc,
                                                  const float* __restrict__ bias,
                                                  const float* __restrict__ lw,
                                                  float* __restrict__ out,
                                                  float* __restrict__ nodedot, int n) {
    int group = threadIdx.x >> 5, lane = threadIdx.x & 31;
    int i = blockIdx.x * 8 + group;
    if (i >= n) return;
    const float4* t4 = (const float4*)t;
    float di = dis[i];
    float4 acc = t4[(size_t)i * 32 + lane];     // self term t'[i]
    int r0 = rowptr[i], r1 = rowptr[i + 1];
    int e = r0;
    for (; e + 1 < r1; e += 2) {
        int s0 = csrc[e], s1 = csrc[e + 1];
        float4 v0 = t4[(size_t)s0 * 32 + lane];
        float4 v1 = t4[(size_t)s1 * 32 + lane];
        acc.x += v0.x + v1.x;
        acc.y += v0.y + v1.y;
        acc.z += v0.z + v1.z;
        acc.w += v0.w + v1.w;
    }
    if (e < r1) {
        int s = csrc[e];
        float4 v = t4[(size_t)s * 32 + lane];
        acc.x += v.x; acc.y += v.y; acc.z += v.z; acc.w += v.w;
    }
    float4 b4 = ((const float4*)bias)[lane];
    acc.x = fmaf(di, acc.x, b4.x);
    acc.y = fmaf(di, acc.y, b4.y);
    acc.z = fmaf(di, acc.z, b4.z);
    acc.w = fmaf(di, acc.w, b4.w);
    if (FINAL) {
        float4 w = ((const float4*)lw)[lane];
        float d = acc.x * w.x + acc.y * w.y + acc.z * w.z + acc.w * w.w;
        #pragma unroll
        for (int o = 16; o > 0; o >>= 1) d += __shfl_down(d, o, 32);
        if (lane == 0) nodedot[i] = d;
    } else {
        ((float4*)(out + (size_t)i * GCN_H))[lane] = acc;
    }
}

// ---------------- pooling (segment reduce over sorted batch) ----------------

__global__ __launch_bounds__(256) void boundary_kernel(const int* __restrict__ batch,
                                                       int* __restrict__ gstart, int n) {
    int i = blockIdx.x * 256 + threadIdx.x;
    if (i >= n) return;
    int b = batch[i];
    int pb = (i == 0) ? -1 : batch[i - 1];
    for (int g = pb + 1; g <= b; g++) gstart[g] = i;
    if (i == n - 1) {
        for (int g = b + 1; g <= GCN_G; g++) gstart[g] = n;
    }
}

__global__ __launch_bounds__(256) void reduce_kernel(const float* __restrict__ nodedot,
                                                     const int* __restrict__ gstart,
                                                     const float* __restrict__ lb,
                                                     float* __restrict__ out) {
    __shared__ float ssum[4];
    int g = blockIdx.x;
    int s = gstart[g], epos = gstart[g + 1];
    int tid = threadIdx.x, lane = tid & 63, wid = tid >> 6;
    float sum = 0.f;
    for (int i = s + tid; i < epos; i += 256) sum += nodedot[i];
    #pragma unroll
    for (int o = 32; o > 0; o >>= 1) sum += __shfl_down(sum, o, 64);
    if (lane == 0) ssum[wid] = sum;
    __syncthreads();
    if (tid == 0) {
        float tot = ssum[0] + ssum[1] + ssum[2] + ssum[3];
        float cnt = (float)max(epos - s, 1);
        float v = tot / cnt + lb[0];
        out[g] = 1.f / (1.f + expf(-v));
    }
}

// ---------------- launch ----------------

extern "C" void kernel_launch(void* const* d_in, const int* in_sizes, int n_in,
                              void* d_out, int out_size, void* d_ws, size_t ws_size,
                              hipStream_t stream) {
    const float* x   = (const float*)d_in[0];
    const int*   ei  = (const int*)d_in[1];
    const int*   bat = (const int*)d_in[2];
    const float* W0  = (const float*)d_in[3];
    const float* b0  = (const float*)d_in[4];
    const float* W1  = (const float*)d_in[5];
    const float* b1  = (const float*)d_in[6];
    const float* W2  = (const float*)d_in[7];
    const float* b2  = (const float*)d_in[8];
    const float* lw  = (const float*)d_in[9];
    const float* lb  = (const float*)d_in[10];
    float* out = (float*)d_out;

    const int N = GCN_N;
    const int E = in_sizes[1] / 2;

    char* ws = (char*)d_ws;
    size_t off = 0;
    auto alloc = [&](size_t bytes) {
        size_t o = off;
        off += (bytes + 255) & ~(size_t)255;
        return o;
    };
    int*   counts  = (int*)(ws + alloc((size_t)N * 4));
    int*   cursor  = (int*)(ws + alloc((size_t)N * 4));
    int*   rowptr  = (int*)(ws + alloc((size_t)(N + 1) * 4));
    float* dis     = (float*)(ws + alloc((size_t)N * 4));
    int*   csrc    = (int*)(ws + alloc((size_t)E * 4));
    float* bufA    = (float*)(ws + alloc((size_t)N * GCN_H * 4));
    float* bufB    = (float*)(ws + alloc((size_t)N * GCN_H * 4));
    float* nodedot = (float*)(ws + alloc((size_t)N * 4));
    int*   gstart  = (int*)(ws + alloc((size_t)(GCN_G + 1) * 4));

    const int* src = ei;
    const int* dst = ei + E;

    hipMemsetAsync(counts, 0, (size_t)N * 4, stream);
    hipMemsetAsync(cursor, 0, (size_t)N * 4, stream);

    count_kernel<<<(E + 255) / 256, 256, 0, stream>>>(dst, counts, E);
    scan_kernel<<<1, 1024, 0, stream>>>(counts, rowptr, dis, N);
    fill_kernel<<<(E + 255) / 256, 256, 0, stream>>>(src, dst, rowptr, cursor, csrc, E);
    boundary_kernel<<<(N + 255) / 256, 256, 0, stream>>>(bat, gstart, N);

    mm0_kernel<<<N / 8, 256, 0, stream>>>(x, W0, dis, bufA, N);
    agg_kernel<0><<<N / 8, 256, 0, stream>>>(bufA, dis, rowptr, csrc, b0, nullptr, bufB, nullptr, N);
    mm128_kernel<<<N / 32, 256, 0, stream>>>(bufB, W1, dis, bufA, N);
    agg_kernel<0><<<N / 8, 256, 0, stream>>>(bufA, dis, rowptr, csrc, b1, nullptr, bufB, nullptr, N);
    mm128_kernel<<<N / 32, 256, 0, stream>>>(bufB, W2, dis, bufA, N);
    agg_kernel<1><<<N / 8, 256, 0, stream>>>(bufA, dis, rowptr, csrc, b2, lw, nullptr, nodedot, N);

    reduce_kernel<<<GCN_G, 256, 0, stream>>>(nodedot, gstart, lb, out);
}

// Round 3
// 383.608 us; speedup vs baseline: 3.0202x; 1.9452x over previous
//
#include <hip/hip_runtime.h>

#define GCN_N 100000
#define GCN_H 128
#define GCN_G 256
#define SCAN_T 1024

// ---------------- CSR build ----------------

__global__ __launch_bounds__(256) void count_kernel(const int* __restrict__ dst,
                                                    int* __restrict__ counts, int E) {
    int e = blockIdx.x * 256 + threadIdx.x;
    if (e < E) atomicAdd(&counts[dst[e]], 1);
}

// phase 1: per-block sums of counts
__global__ __launch_bounds__(SCAN_T) void scan_partial_kernel(const int* __restrict__ counts,
                                                              int* __restrict__ bsum, int n) {
    __shared__ int wsums[16];
    int tid = threadIdx.x;
    int idx = blockIdx.x * SCAN_T + tid;
    int v = (idx < n) ? counts[idx] : 0;
    #pragma unroll
    for (int o = 32; o > 0; o >>= 1) v += __shfl_down(v, o, 64);
    if ((tid & 63) == 0) wsums[tid >> 6] = v;
    __syncthreads();
    if (tid == 0) {
        int s = 0;
        #pragma unroll
        for (int w = 0; w < 16; w++) s += wsums[w];
        bsum[blockIdx.x] = s;
    }
}

// phase 2: serial exclusive scan of block sums (nb ~ 98, trivial)
__global__ void scan_offsets_kernel(const int* __restrict__ bsum,
                                    int* __restrict__ boffs,
                                    int* __restrict__ rowptr, int nb, int n) {
    if (threadIdx.x == 0 && blockIdx.x == 0) {
        int run = 0;
        for (int i = 0; i < nb; i++) { boffs[i] = run; run += bsum[i]; }
        boffs[nb] = run;
        rowptr[n] = run;
    }
}

// phase 3: block-level exclusive scan + add block offset; also deg -> dis
__global__ __launch_bounds__(SCAN_T) void scan_block_kernel(const int* __restrict__ counts,
                                                            const int* __restrict__ boffs,
                                                            int* __restrict__ rowptr,
                                                            float* __restrict__ dis, int n) {
    __shared__ int wsums[16];
    int tid = threadIdx.x;
    int lane = tid & 63, wid = tid >> 6;
    int idx = blockIdx.x * SCAN_T + tid;
    int v = (idx < n) ? counts[idx] : 0;
    int iv = v;
    #pragma unroll
    for (int d = 1; d < 64; d <<= 1) {
        int x = __shfl_up(iv, d, 64);
        if (lane >= d) iv += x;
    }
    if (lane == 63) wsums[wid] = iv;
    __syncthreads();
    if (wid == 0) {
        int wv = (lane < 16) ? wsums[lane] : 0;
        #pragma unroll
        for (int d = 1; d < 16; d <<= 1) {
            int x = __shfl_up(wv, d, 64);
            if (lane >= d) wv += x;
        }
        if (lane < 16) wsums[lane] = wv;
    }
    __syncthreads();
    int woff = (wid > 0) ? wsums[wid - 1] : 0;
    if (idx < n) {
        rowptr[idx] = boffs[blockIdx.x] + woff + iv - v;   // exclusive
        dis[idx] = rsqrtf((float)(v + 1));                 // deg = indeg + self-loop
    }
}

__global__ __launch_bounds__(256) void fill_kernel(const int* __restrict__ src,
                                                   const int* __restrict__ dst,
                                                   const int* __restrict__ rowptr,
                                                   int* __restrict__ cursor,
                                                   int* __restrict__ csrc, int E) {
    int e = blockIdx.x * 256 + threadIdx.x;
    if (e < E) {
        int d = dst[e];
        int pos = rowptr[d] + atomicAdd(&cursor[d], 1);
        csrc[pos] = src[e];
    }
}

// ---------------- layer 0: 5-dim scaled copy + aggregation ----------------

// xsp[i][0..5) = dis[i] * x[i][0..5)   (padded to 8 floats/row)
__global__ __launch_bounds__(256) void xscale_kernel(const float* __restrict__ x,
                                                     const float* __restrict__ dis,
                                                     float* __restrict__ xsp, int n) {
    int i = blockIdx.x * 256 + threadIdx.x;
    if (i >= n) return;
    float di = dis[i];
    float4 a;
    a.x = x[(size_t)i * 5 + 0] * di;
    a.y = x[(size_t)i * 5 + 1] * di;
    a.z = x[(size_t)i * 5 + 2] * di;
    a.w = x[(size_t)i * 5 + 3] * di;
    float a4 = x[(size_t)i * 5 + 4] * di;
    ((float4*)(xsp + (size_t)i * 8))[0] = a;
    xsp[(size_t)i * 8 + 4] = a4;
}

// a0[i] = dis[i] * (xsp[i] + sum_src xsp[src])   (5-dim, padded rows)
__global__ __launch_bounds__(256) void aggx_kernel(const float* __restrict__ xsp,
                                                   const float* __restrict__ dis,
                                                   const int* __restrict__ rowptr,
                                                   const int* __restrict__ csrc,
                                                   float* __restrict__ a0p, int n) {
    int i = blockIdx.x * 256 + threadIdx.x;
    if (i >= n) return;
    float4 acc = ((const float4*)(xsp + (size_t)i * 8))[0];
    float acc4 = xsp[(size_t)i * 8 + 4];
    int r0 = rowptr[i], r1 = rowptr[i + 1];
    for (int e = r0; e < r1; e++) {
        int s = csrc[e];
        float4 v = ((const float4*)(xsp + (size_t)s * 8))[0];
        acc.x += v.x; acc.y += v.y; acc.z += v.z; acc.w += v.w;
        acc4 += xsp[(size_t)s * 8 + 4];
    }
    float di = dis[i];
    acc.x *= di; acc.y *= di; acc.z *= di; acc.w *= di; acc4 *= di;
    ((float4*)(a0p + (size_t)i * 8))[0] = acc;
    a0p[(size_t)i * 8 + 4] = acc4;
}

// ---------------- fused mm: t1 = dis ⊙ (relu(a0@W0 + b0) @ W1) ----------------

__global__ __launch_bounds__(256) void mmfused_kernel(const float* __restrict__ a0p,
                                                      const float* __restrict__ W0,
                                                      const float* __restrict__ b0,
                                                      const float* __restrict__ W1,
                                                      const float* __restrict__ dis,
                                                      float* __restrict__ t1, int n) {
    __shared__ __align__(16) float sW[128 * 128];   // 64 KB (W1)
    __shared__ __align__(16) float sH[32 * 128];    // 16 KB (relu'd h1 rows)
    int tid = threadIdx.x;
    int group = tid >> 5, lane = tid & 31;

    // W0/b0 fragments into registers (broadcast L2 reads)
    float4 w0r[5];
    #pragma unroll
    for (int j = 0; j < 5; j++) w0r[j] = ((const float4*)(W0 + j * 128))[lane];
    float4 b0r = ((const float4*)b0)[lane];

    // stage W1
    const float4* W14 = (const float4*)W1;
    float4* sW4 = (float4*)sW;
    for (int i = tid; i < 128 * 32; i += 256) sW4[i] = W14[i];

    int rowBase = blockIdx.x * 32;
    int r0 = group * 4;
    // compute h1 for this group's 4 rows
    #pragma unroll
    for (int rr = 0; rr < 4; rr++) {
        int row = rowBase + r0 + rr;
        const float* ar = a0p + (size_t)row * 8;
        float4 h = b0r;
        #pragma unroll
        for (int j = 0; j < 5; j++) {
            float aj = ar[j];
            h.x = fmaf(aj, w0r[j].x, h.x);
            h.y = fmaf(aj, w0r[j].y, h.y);
            h.z = fmaf(aj, w0r[j].z, h.z);
            h.w = fmaf(aj, w0r[j].w, h.w);
        }
        h.x = fmaxf(h.x, 0.f); h.y = fmaxf(h.y, 0.f);
        h.z = fmaxf(h.z, 0.f); h.w = fmaxf(h.w, 0.f);
        ((float4*)(sH + (r0 + rr) * 128))[lane] = h;
    }
    __syncthreads();

    float4 acc0 = make_float4(0.f,0.f,0.f,0.f);
    float4 acc1 = make_float4(0.f,0.f,0.f,0.f);
    float4 acc2 = make_float4(0.f,0.f,0.f,0.f);
    float4 acc3 = make_float4(0.f,0.f,0.f,0.f);
    const float* a0ptr = sH + (r0 + 0) * 128;
    const float* a1ptr = sH + (r0 + 1) * 128;
    const float* a2ptr = sH + (r0 + 2) * 128;
    const float* a3ptr = sH + (r0 + 3) * 128;
    #pragma unroll 8
    for (int k = 0; k < 128; k++) {
        float4 w = sW4[k * 32 + lane];
        float a0 = a0ptr[k], a1 = a1ptr[k], a2 = a2ptr[k], a3 = a3ptr[k];
        acc0.x = fmaf(a0, w.x, acc0.x); acc0.y = fmaf(a0, w.y, acc0.y);
        acc0.z = fmaf(a0, w.z, acc0.z); acc0.w = fmaf(a0, w.w, acc0.w);
        acc1.x = fmaf(a1, w.x, acc1.x); acc1.y = fmaf(a1, w.y, acc1.y);
        acc1.z = fmaf(a1, w.z, acc1.z); acc1.w = fmaf(a1, w.w, acc1.w);
        acc2.x = fmaf(a2, w.x, acc2.x); acc2.y = fmaf(a2, w.y, acc2.y);
        acc2.z = fmaf(a2, w.z, acc2.z); acc2.w = fmaf(a2, w.w, acc2.w);
        acc3.x = fmaf(a3, w.x, acc3.x); acc3.y = fmaf(a3, w.y, acc3.y);
        acc3.z = fmaf(a3, w.z, acc3.z); acc3.w = fmaf(a3, w.w, acc3.w);
    }
    float d0 = dis[rowBase + r0 + 0], d1 = dis[rowBase + r0 + 1];
    float d2 = dis[rowBase + r0 + 2], d3 = dis[rowBase + r0 + 3];
    acc0.x *= d0; acc0.y *= d0; acc0.z *= d0; acc0.w *= d0;
    acc1.x *= d1; acc1.y *= d1; acc1.z *= d1; acc1.w *= d1;
    acc2.x *= d2; acc2.y *= d2; acc2.z *= d2; acc2.w *= d2;
    acc3.x *= d3; acc3.y *= d3; acc3.z *= d3; acc3.w *= d3;
    ((float4*)(t1 + (size_t)(rowBase + r0 + 0) * GCN_H))[lane] = acc0;
    ((float4*)(t1 + (size_t)(rowBase + r0 + 1) * GCN_H))[lane] = acc1;
    ((float4*)(t1 + (size_t)(rowBase + r0 + 2) * GCN_H))[lane] = acc2;
    ((float4*)(t1 + (size_t)(rowBase + r0 + 3) * GCN_H))[lane] = acc3;
}

// ---------------- w2l = W2 @ lin_w, c2 = b2 . lin_w ----------------

__global__ __launch_bounds__(256) void w2l_kernel(const float* __restrict__ W2,
                                                  const float* __restrict__ b2,
                                                  const float* __restrict__ lw,
                                                  float* __restrict__ w2l,
                                                  float* __restrict__ c2) {
    __shared__ float slw[128];
    int tid = threadIdx.x;
    if (tid < 128) slw[tid] = lw[tid];
    __syncthreads();
    if (tid < 128) {
        float s = 0.f;
        #pragma unroll 8
        for (int j = 0; j < 128; j++) s = fmaf(W2[tid * 128 + j], slw[j], s);
        w2l[tid] = s;
    } else if (tid == 128) {
        float s = 0.f;
        for (int j = 0; j < 128; j++) s = fmaf(b2[j], slw[j], s);
        c2[0] = s;
    }
}

// ---------------- layer-1 aggregation fused with layer-2 dot ----------------
// conv1[i] = dis[i]*(t1[i] + sum t1[src]) + b1 ;  z[i] = dis[i] * dot(relu(conv1[i]), w2l)
__global__ __launch_bounds__(256) void agg1_kernel(const float* __restrict__ t1,
                                                   const float* __restrict__ dis,
                                                   const int* __restrict__ rowptr,
                                                   const int* __restrict__ csrc,
                                                   const float* __restrict__ b1,
                                                   const float* __restrict__ w2l,
                                                   float* __restrict__ z, int n) {
    int group = threadIdx.x >> 5, lane = threadIdx.x & 31;
    int i = blockIdx.x * 8 + group;
    if (i >= n) return;
    const float4* t4 = (const float4*)t1;
    float4 acc = t4[(size_t)i * 32 + lane];     // self term
    int r0 = rowptr[i], r1 = rowptr[i + 1];
    int e = r0;
    for (; e + 3 < r1; e += 4) {
        int s0 = csrc[e], s1 = csrc[e + 1], s2 = csrc[e + 2], s3 = csrc[e + 3];
        float4 v0 = t4[(size_t)s0 * 32 + lane];
        float4 v1 = t4[(size_t)s1 * 32 + lane];
        float4 v2 = t4[(size_t)s2 * 32 + lane];
        float4 v3 = t4[(size_t)s3 * 32 + lane];
        acc.x += (v0.x + v1.x) + (v2.x + v3.x);
        acc.y += (v0.y + v1.y) + (v2.y + v3.y);
        acc.z += (v0.z + v1.z) + (v2.z + v3.z);
        acc.w += (v0.w + v1.w) + (v2.w + v3.w);
    }
    for (; e < r1; e++) {
        int s = csrc[e];
        float4 v = t4[(size_t)s * 32 + lane];
        acc.x += v.x; acc.y += v.y; acc.z += v.z; acc.w += v.w;
    }
    float di = dis[i];
    float4 b4 = ((const float4*)b1)[lane];
    acc.x = fmaf(di, acc.x, b4.x);
    acc.y = fmaf(di, acc.y, b4.y);
    acc.z = fmaf(di, acc.z, b4.z);
    acc.w = fmaf(di, acc.w, b4.w);
    acc.x = fmaxf(acc.x, 0.f); acc.y = fmaxf(acc.y, 0.f);
    acc.z = fmaxf(acc.z, 0.f); acc.w = fmaxf(acc.w, 0.f);
    float4 w = ((const float4*)w2l)[lane];
    float d = acc.x * w.x + acc.y * w.y + acc.z * w.z + acc.w * w.w;
    #pragma unroll
    for (int o = 16; o > 0; o >>= 1) d += __shfl_down(d, o, 32);
    if (lane == 0) z[i] = di * d;
}

// ---------------- layer-2 scalar aggregation ----------------
// nd[i] = dis[i] * (z[i] + sum z[src])
__global__ __launch_bounds__(256) void aggz_kernel(const float* __restrict__ z,
                                                   const float* __restrict__ dis,
                                                   const int* __restrict__ rowptr,
                                                   const int* __restrict__ csrc,
                                                   float* __restrict__ nd, int n) {
    int i = blockIdx.x * 256 + threadIdx.x;
    if (i >= n) return;
    float acc = z[i];
    int r0 = rowptr[i], r1 = rowptr[i + 1];
    int e = r0;
    for (; e + 3 < r1; e += 4) {
        acc += (z[csrc[e]] + z[csrc[e + 1]]) + (z[csrc[e + 2]] + z[csrc[e + 3]]);
    }
    for (; e < r1; e++) acc += z[csrc[e]];
    nd[i] = dis[i] * acc;
}

// ---------------- pooling (segment reduce over sorted batch) ----------------

__global__ __launch_bounds__(256) void boundary_kernel(const int* __restrict__ batch,
                                                       int* __restrict__ gstart, int n) {
    int i = blockIdx.x * 256 + threadIdx.x;
    if (i >= n) return;
    int b = batch[i];
    int pb = (i == 0) ? -1 : batch[i - 1];
    for (int g = pb + 1; g <= b; g++) gstart[g] = i;
    if (i == n - 1) {
        for (int g = b + 1; g <= GCN_G; g++) gstart[g] = n;
    }
}

__global__ __launch_bounds__(256) void reduce_kernel(const float* __restrict__ nd,
                                                     const int* __restrict__ gstart,
                                                     const float* __restrict__ c2,
                                                     const float* __restrict__ lb,
                                                     float* __restrict__ out) {
    __shared__ float ssum[4];
    int g = blockIdx.x;
    int s = gstart[g], epos = gstart[g + 1];
    int tid = threadIdx.x, lane = tid & 63, wid = tid >> 6;
    float sum = 0.f;
    for (int i = s + tid; i < epos; i += 256) sum += nd[i];
    #pragma unroll
    for (int o = 32; o > 0; o >>= 1) sum += __shfl_down(sum, o, 64);
    if (lane == 0) ssum[wid] = sum;
    __syncthreads();
    if (tid == 0) {
        float tot = ssum[0] + ssum[1] + ssum[2] + ssum[3];
        float cnt = (float)max(epos - s, 1);
        float v = tot / cnt + c2[0] + lb[0];
        out[g] = 1.f / (1.f + expf(-v));
    }
}

// ---------------- launch ----------------

extern "C" void kernel_launch(void* const* d_in, const int* in_sizes, int n_in,
                              void* d_out, int out_size, void* d_ws, size_t ws_size,
                              hipStream_t stream) {
    const float* x   = (const float*)d_in[0];
    const int*   ei  = (const int*)d_in[1];
    const int*   bat = (const int*)d_in[2];
    const float* W0  = (const float*)d_in[3];
    const float* b0  = (const float*)d_in[4];
    const float* W1  = (const float*)d_in[5];
    const float* b1  = (const float*)d_in[6];
    const float* W2  = (const float*)d_in[7];
    const float* b2  = (const float*)d_in[8];
    const float* lw  = (const float*)d_in[9];
    const float* lb  = (const float*)d_in[10];
    float* out = (float*)d_out;

    const int N = GCN_N;
    const int E = in_sizes[1] / 2;
    const int NB = (N + SCAN_T - 1) / SCAN_T;

    char* ws = (char*)d_ws;
    size_t off = 0;
    auto alloc = [&](size_t bytes) {
        size_t o = off;
        off += (bytes + 255) & ~(size_t)255;
        return o;
    };
    int*   counts  = (int*)(ws + alloc((size_t)N * 4));
    int*   cursor  = (int*)(ws + alloc((size_t)N * 4));
    int*   rowptr  = (int*)(ws + alloc((size_t)(N + 1) * 4));
    float* dis     = (float*)(ws + alloc((size_t)N * 4));
    int*   csrc    = (int*)(ws + alloc((size_t)E * 4));
    float* xsp     = (float*)(ws + alloc((size_t)N * 8 * 4));
    float* a0p     = (float*)(ws + alloc((size_t)N * 8 * 4));
    float* t1      = (float*)(ws + alloc((size_t)N * GCN_H * 4));
    float* z       = (float*)(ws + alloc((size_t)N * 4));
    float* nd      = (float*)(ws + alloc((size_t)N * 4));
    int*   gstart  = (int*)(ws + alloc((size_t)(GCN_G + 1) * 4));
    int*   bsum    = (int*)(ws + alloc((size_t)NB * 4));
    int*   boffs   = (int*)(ws + alloc((size_t)(NB + 1) * 4));
    float* w2l     = (float*)(ws + alloc(128 * 4));
    float* c2      = (float*)(ws + alloc(4));

    const int* src = ei;
    const int* dst = ei + E;

    hipMemsetAsync(counts, 0, (size_t)N * 4, stream);
    hipMemsetAsync(cursor, 0, (size_t)N * 4, stream);

    count_kernel<<<(E + 255) / 256, 256, 0, stream>>>(dst, counts, E);
    scan_partial_kernel<<<NB, SCAN_T, 0, stream>>>(counts, bsum, N);
    scan_offsets_kernel<<<1, 64, 0, stream>>>(bsum, boffs, rowptr, NB, N);
    scan_block_kernel<<<NB, SCAN_T, 0, stream>>>(counts, boffs, rowptr, dis, N);
    fill_kernel<<<(E + 255) / 256, 256, 0, stream>>>(src, dst, rowptr, cursor, csrc, E);
    boundary_kernel<<<(N + 255) / 256, 256, 0, stream>>>(bat, gstart, N);
    w2l_kernel<<<1, 256, 0, stream>>>(W2, b2, lw, w2l, c2);

    xscale_kernel<<<(N + 255) / 256, 256, 0, stream>>>(x, dis, xsp, N);
    aggx_kernel<<<(N + 255) / 256, 256, 0, stream>>>(xsp, dis, rowptr, csrc, a0p, N);
    mmfused_kernel<<<N / 32, 256, 0, stream>>>(a0p, W0, b0, W1, dis, t1, N);
    agg1_kernel<<<N / 8, 256, 0, stream>>>(t1, dis, rowptr, csrc, b1, w2l, z, N);
    aggz_kernel<<<(N + 255) / 256, 256, 0, stream>>>(z, dis, rowptr, csrc, nd, N);

    reduce_kernel<<<GCN_G, 256, 0, stream>>>(nd, gstart, c2, lb, out);
}